// Round 10
// baseline (153.442 us; speedup 1.0000x reference)
//
#include <hip/hip_runtime.h>

// BERT joint NER+relation head on MI355X (gfx950).
// Inputs: fp32. Output: fp32 flat [tags(1024) | scores(3145728)].
// R25: THREE launches (main / fuse / scorer). ner folded into main_kernel:
// blocks 0-255 compute ner then release-fence + one atomicAdd(flag); the
// viterbi block RMW-polls flag==256 (ONE spinner -- R19's proven protocol
// without its 401-spinner LLC serialization pathology). All numerics
// bitwise = R24 (passed, 142.1us). Viterbi keeps ds_bpermute gather tree +
// setprio. fuse (R15-exact) + scorer (R20-exact) unchanged.
// 765 blocks <= 768 co-resident slots (LDS 46848 -> 3/CU); producers never
// wait -> deadlock-free regardless of scheduling.

typedef unsigned short ushort_t;
typedef __attribute__((ext_vector_type(8))) short bf16x8;
typedef __attribute__((ext_vector_type(4))) float f32x4;
typedef __attribute__((ext_vector_type(2))) float f32x2;
typedef __attribute__((ext_vector_type(4))) int i32x4;
typedef unsigned long long u64;

#define C2F 2.8853900817779268f  // 2*log2(e)

// workspace offsets (bytes), all 16-aligned (ws_size = 256 MiB, plenty)
#define WS_UW2   0u         // ushort [1024][1600] : bf16(exp2(C2*(embed@[U|W]+bias))), lab-fused by K2
#define WS_NER   3276800u   // float  [1024][9]
#define WS_VFRAG 3313664u   // ushort [25][64][8]  : V as 16x16x32 B-fragments (bf16)
#define WS_LAB2  3339264u   // float  [9][1600]    : exp2(C2*(label_emb@[U|W][768:]))
#define WS_TAGS  3396864u   // int    [1024]
#define WS_CSUM  3400960u   // float  [12]         : colsum_r = sum_h V[h,r]
#define WS_FLAG  3401024u   // unsigned : ner-done counter (memset 0 each launch)

__device__ __forceinline__ unsigned f2b(float f){          // RNE, finite only
  unsigned u = __float_as_uint(f);
  return (u + 0x7FFFu + ((u>>16)&1u)) >> 16;
}
__device__ __forceinline__ unsigned pkbf16(float hi, float lo){
  return __builtin_amdgcn_perm(__float_as_uint(hi), __float_as_uint(lo), 0x07060302u);
}
__device__ __forceinline__ float lo16(int v){ return __uint_as_float(((unsigned)v)<<16); }
__device__ __forceinline__ float hi16g(int v){ return __uint_as_float((unsigned)v); }
// compose packed tag-functions (9 nibbles): R[t] = F[H[t]]
__device__ __forceinline__ u64 fcompose(u64 F, u64 H){
  u64 R = 0;
  #pragma unroll
  for (int t=0;t<9;t++){
    unsigned h = (unsigned)(H >> (4*t)) & 15u;
    unsigned v = (unsigned)(F >> (4*h)) & 15u;
    R |= (u64)v << (4*t);
  }
  return R;
}

// -- K2: ner+flag || GEMM || viterbi(spin) || lab2 || vfrag || csum (765) --
__global__ __launch_bounds__(256) void main_kernel(
    const float* __restrict__ embed, const float* __restrict__ lw,
    const float* __restrict__ lb,    const float* __restrict__ lemb,
    const float* __restrict__ uw,    const float* __restrict__ ub,
    const float* __restrict__ ww,    const float* __restrict__ wb,
    const float* __restrict__ vw,
    const float* __restrict__ start_t, const float* __restrict__ trans,
    const float* __restrict__ end_t,
    char* __restrict__ ws, float* __restrict__ out_tags)
{
  __shared__ char smem[46848];     // union: GEMM As/Bs (10496) | viterbi (46848) | csum part
  int bx = blockIdx.x, tid = threadIdx.x;
  unsigned* flag = (unsigned*)(ws + WS_FLAG);

  if (bx < 256) {                        // ---- ner = embed@linear_w + b (1 wave/row) + flag
    float* ner = (float*)(ws + WS_NER);
    int w = tid >> 6, lane = tid & 63;
    int row = bx*4 + w;                  // < 1024
    float acc[9];
    #pragma unroll
    for (int i=0;i<9;i++) acc[i]=0.f;
    const float* erow = embed + row*768;
    for (int kk=0; kk<12; kk++) {
      int k = kk*64 + lane;
      float e = erow[k];
      #pragma unroll
      for (int i=0;i<9;i++) acc[i] = __builtin_fmaf(e, lw[k*9+i], acc[i]);
    }
    #pragma unroll
    for (int i=0;i<9;i++) {
      float v = acc[i];
      for (int off=32; off>0; off>>=1) v += __shfl_down(v, off);
      if (lane == 0) ner[row*9+i] = v + lb[i];
    }
    __syncthreads();                     // all waves' stores drained to L2
    if (tid == 0) {
      __threadfence();                   // release: XCD-L2 -> LLC
      __hip_atomic_fetch_add(flag, 1u, __ATOMIC_RELAXED, __HIP_MEMORY_SCOPE_AGENT);
    }
  } else if (bx < 656) {                 // ---- GEMM, plain epilogue (R15-exact)
    ushort_t (*As)[40] = (ushort_t(*)[40])smem;            // [m][k] +8 pad
    ushort_t (*Bs)[42] = (ushort_t(*)[42])(smem + 5120);   // [n][k] +10 pad
    ushort_t* uw2 = (ushort_t*)(ws + WS_UW2);
    int bmx = bx - 256;
    int bm = bmx & 15, bn = bmx >> 4;
    int M0 = bm*64, N0 = bn*64;
    int w = tid>>6, lane = tid&63;
    int wr = w>>1, wc = w&1;
    int m16 = lane&15, quad = lane>>4;
    int nl = tid>>2, k8 = (tid&3)<<3;
    int bnn = tid & 63, bw = tid >> 6;
    int gn = N0 + bnn;
    const float* bsrc = uw; int bcol = 0; bool bzero = true;
    if (gn < 798)                    { bsrc = uw; bcol = gn;     bzero = false; }
    else if (gn >= 800 && gn < 1598) { bsrc = ww; bcol = gn-800; bzero = false; }

    f32x4 acc[2][2];
    #pragma unroll
    for (int mi=0;mi<2;mi++)
      #pragma unroll
      for (int ni=0;ni<2;ni++) acc[mi][ni] = (f32x4){0.f,0.f,0.f,0.f};

    f32x4 a_lo, a_hi; float bvals[8];
    {
      const float* ap = &embed[(M0+nl)*768 + k8];
      a_lo = *(const f32x4*)ap; a_hi = *(const f32x4*)(ap+4);
      #pragma unroll
      for (int r=0;r<4;r++) {
        int kk = r*8 + bw*2;
        bvals[2*r]   = bzero ? 0.f : bsrc[(kk  )*798 + bcol];
        bvals[2*r+1] = bzero ? 0.f : bsrc[(kk+1)*798 + bcol];
      }
    }
    for (int k0=0; k0<768; k0+=32) {
      i32x4 av = (i32x4){ (int)pkbf16(a_lo.y,a_lo.x), (int)pkbf16(a_lo.w,a_lo.z),
                          (int)pkbf16(a_hi.y,a_hi.x), (int)pkbf16(a_hi.w,a_hi.z) };
      *(i32x4*)&As[nl][k8] = av;
      #pragma unroll
      for (int r=0;r<4;r++) {
        int kk = r*8 + bw*2;
        *(unsigned*)&Bs[bnn][kk] = pkbf16(bvals[2*r+1], bvals[2*r]);
      }
      __syncthreads();
      if (k0 + 32 < 768) {
        const float* ap = &embed[(M0+nl)*768 + k0 + 32 + k8];
        a_lo = *(const f32x4*)ap; a_hi = *(const f32x4*)(ap+4);
        #pragma unroll
        for (int r=0;r<4;r++) {
          int kk = r*8 + bw*2;
          bvals[2*r]   = bzero ? 0.f : bsrc[(k0+32+kk  )*798 + bcol];
          bvals[2*r+1] = bzero ? 0.f : bsrc[(k0+32+kk+1)*798 + bcol];
        }
      }
      bf16x8 a0 = *(const bf16x8*)&As[wr*32      + m16][quad*8];
      bf16x8 a1 = *(const bf16x8*)&As[wr*32 + 16 + m16][quad*8];
      bf16x8 b0 = *(const bf16x8*)&Bs[wc*32      + m16][quad*8];
      bf16x8 b1 = *(const bf16x8*)&Bs[wc*32 + 16 + m16][quad*8];
      acc[0][0] = __builtin_amdgcn_mfma_f32_16x16x32_bf16(a0,b0,acc[0][0],0,0,0);
      acc[0][1] = __builtin_amdgcn_mfma_f32_16x16x32_bf16(a0,b1,acc[0][1],0,0,0);
      acc[1][0] = __builtin_amdgcn_mfma_f32_16x16x32_bf16(a1,b0,acc[1][0],0,0,0);
      acc[1][1] = __builtin_amdgcn_mfma_f32_16x16x32_bf16(a1,b1,acc[1][1],0,0,0);
      __syncthreads();
    }
    #pragma unroll
    for (int mi=0;mi<2;mi++)
      #pragma unroll
      for (int ni=0;ni<2;ni++)
        #pragma unroll
        for (int reg=0;reg<4;reg++) {
          int gm = M0 + wr*32 + mi*16 + quad*4 + reg;
          int go = N0 + wc*32 + ni*16 + m16;
          float bias = 0.f;
          if (go < 798) bias = ub[go];
          else if (go >= 800 && go < 1598) bias = wb[go-800];
          float v = (acc[mi][ni][reg] + bias) * C2F;
          uw2[gm*1600 + go] = (ushort_t)f2b(__builtin_amdgcn_exp2f(v));
        }
  } else if (bx == 656) {                // ---- viterbi (spin for ner, then run)
    if (tid == 0) {                      // ONE spinner: RMW-poll at LLC (R19-proven fresh)
      while (__hip_atomic_fetch_add(flag, 0u, __ATOMIC_RELAXED,
                                    __HIP_MEMORY_SCOPE_AGENT) < 256u)
        __builtin_amdgcn_s_sleep(8);
      __threadfence();                   // acquire: inv stale L1/L2
    }
    __syncthreads();

    float* scores = (float*)smem;                    // [4][256][9] f32, 36864 B
    u64* pk = (u64*)(smem + 36864);                  // [4][256] packed funcs
    float* trl = (float*)(smem + 45056);             // [81]
    int* lastArr = (int*)(smem + 45384);             // [4]
    unsigned char* tagbuf = (unsigned char*)(smem + 45400);  // [4][256]
    const float* ner = (const float*)(ws + WS_NER);
    int* tags = (int*)(ws + WS_TAGS);
    int w = tid>>6, lane = tid&63;
    int b = w;
    int tt = lane < 9 ? lane : 8;
    if (tid < 81) trl[tid] = trans[tid];

    float tcol[9];
    #pragma unroll
    for (int p=0;p<9;p++) tcol[p] = trans[p*9+tt];
    const float* nb = ner + (b*256)*9 + tt;
    float score = start_t[tt] + nb[0];
    if (lane < 9) scores[(b*256 + 0)*9 + tt] = score;

    float cur[15], nxt[15];
    #pragma unroll
    for (int j=0;j<15;j++) cur[j] = nb[(1+j)*9];
    // gather lane p's score via explicit ds_bpermute (9 back-to-back issues,
    // one lgkm wait); bits identical to readlane/shfl path.
    #define GATHER(p) __uint_as_float(__builtin_amdgcn_ds_bpermute((p)<<2, __float_as_uint(score)))
    __builtin_amdgcn_s_setprio(1);
    for (int ch=0; ch<17; ch++) {
      int sb = 1 + ch*15;
      if (ch < 16) {
        #pragma unroll
        for (int j=0;j<15;j++) nxt[j] = nb[(sb+15+j)*9];
      }
      #pragma unroll
      for (int j=0;j<15;j++) {
        float g0=GATHER(0), g1=GATHER(1), g2=GATHER(2),
              g3=GATHER(3), g4=GATHER(4), g5=GATHER(5),
              g6=GATHER(6), g7=GATHER(7), g8=GATHER(8);
        float m0 = fmaxf(fmaxf(g0+tcol[0], g1+tcol[1]), g2+tcol[2]);
        float m1 = fmaxf(fmaxf(g3+tcol[3], g4+tcol[4]), g5+tcol[5]);
        float m2 = fmaxf(fmaxf(g6+tcol[6], g7+tcol[7]), g8+tcol[8]);
        score = fmaxf(fmaxf(m0,m1),m2) + cur[j];
        if (lane < 9) scores[(b*256 + sb + j)*9 + tt] = score;
      }
      #pragma unroll
      for (int j=0;j<15;j++) cur[j] = nxt[j];
    }
    __builtin_amdgcn_s_setprio(0);
    #undef GATHER
    {
      float fin = score + end_t[tt];
      #define RLF(p) __uint_as_float(__builtin_amdgcn_readlane(__float_as_uint(fin), p))
      float bv = RLF(0); int ba = 0;
      #pragma unroll
      for (int p=1;p<9;p++) { float v = RLF(p); if (v > bv) { bv = v; ba = p; } }
      if (lane == 0) lastArr[b] = ba;
      #undef RLF
    }
    __syncthreads();

    for (int idx = tid; idx < 1024; idx += 256) {
      int bb = idx >> 8, s = idx & 255;
      u64 f;
      if (s == 255) f = 0x876543210ULL;              // identity
      else {
        const float* srow = &scores[(bb*256 + s)*9];
        float sp[9];
        #pragma unroll
        for (int p=0;p<9;p++) sp[p] = srow[p];
        f = 0;
        #pragma unroll
        for (int t=0;t<9;t++) {
          float best = sp[0] + trl[t]; int arg = 0;
          #pragma unroll
          for (int p=1;p<9;p++) {
            float v = sp[p] + trl[p*9 + t];
            if (v > best) { best = v; arg = p; }
          }
          f |= (u64)arg << (4*t);
        }
      }
      pk[bb*256 + s] = f;
    }
    __syncthreads();

    if (tid < 64) {
      int cb = tid >> 4, c = tid & 15;
      u64 fs[16];
      #pragma unroll
      for (int j=0;j<16;j++) fs[j] = pk[cb*256 + c*16 + j];
      u64 G = fs[15];
      #pragma unroll
      for (int j=14;j>=0;j--) G = fcompose(fs[j], G);
      u64 F = G;
      #pragma unroll
      for (int d=1; d<16; d<<=1) {
        u64 H = __shfl(F, tid + d);
        if (c + d < 16) F = fcompose(F, H);
      }
      int last = lastArr[cb];
      u64 Hn = __shfl(F, (c==15) ? tid : tid+1);
      unsigned t_cur = (c==15) ? (unsigned)last
                               : (unsigned)((Hn >> (4*last)) & 15u);
      #pragma unroll
      for (int j=15;j>=0;j--) {
        t_cur = (unsigned)((fs[j] >> (4*t_cur)) & 15u);
        tagbuf[cb*256 + c*16 + j] = (unsigned char)t_cur;
      }
    }
    __syncthreads();

    for (int idx = tid; idx < 1024; idx += 256) {
      int tg = (int)tagbuf[idx];
      tags[idx] = tg;
      out_tags[idx] = (float)tg;
    }
  } else if (bx < 714) {                 // ---- lab2[g][n] = exp2(C2*lemb[g]@[U|W][768:,n])
    float* lab2 = (float*)(ws + WS_LAB2);
    int idx = (bx-657)*256 + tid;
    if (idx < 14400) {
      int g = idx / 1600, n = idx - g*1600;
      const float* X = (n < 800) ? uw : ww;
      int nn = (n < 800) ? n : (n - 800);
      float v = 1.0f;                    // pad columns: multiplicative identity
      if (nn < 798) {
        float s = 0.f;
        #pragma unroll                   // pipeline the 30 strided loads
        for (int l=0;l<30;l++)
          s = __builtin_fmaf(lemb[g*30+l], X[(768+l)*798 + nn], s);
        v = __builtin_amdgcn_exp2f(s * C2F);
      }
      lab2[idx] = v;
    }
  } else if (bx < 764) {                 // ---- V B-fragments
    ushort_t* vf = (ushort_t*)(ws + WS_VFRAG);
    int idx = (bx-714)*256 + tid;        // < 12800
    if (idx < 12800) {
      int jj = idx & 7, lane = (idx>>3) & 63, c = idx >> 9;
      int h = c*32 + ((lane>>4)<<3) + jj;
      int n = lane & 15;
      vf[idx] = (h < 798 && n < 12) ? (ushort_t)f2b(vw[h*12 + n]) : (ushort_t)0;
    }
  } else {                               // ---- csum[r] = sum_h V[h,r], 256-thread + LDS reduce
    float* part = (float*)smem;          // [16][12]
    float* csum = (float*)(ws + WS_CSUM);
    int r = tid & 15, sub = tid >> 4;    // 16 subs x 16 slots (r<12 active)
    if (r < 12 && sub < 16) {
      float s = 0.f;
      for (int h = sub; h < 798; h += 16) s += vw[h*12 + r];
      part[sub*12 + r] = s;
    }
    __syncthreads();
    if (tid < 12) {
      float t = 0.f;
      #pragma unroll
      for (int k = 0; k < 16; k++) t += part[k*12 + tid];
      csum[tid] = t;
    }
  }
}

// ---------------------------------- K3: fuse Elab[tag] into uw2 (in place)
__global__ __launch_bounds__(256) void fuse_kernel(char* __restrict__ ws)
{
  ushort_t* uw2      = (ushort_t*)(ws + WS_UW2);
  const float* lab2  = (const float*)(ws + WS_LAB2);
  const int* tags    = (const int*)(ws + WS_TAGS);
  int idx = blockIdx.x*256 + threadIdx.x;          // < 204800 vec8 chunks
  int row = idx / 200, c8 = idx - row*200, kc = c8*8;
  int tag = tags[row];
  ushort_t* p = uw2 + (size_t)row*1600 + kc;
  i32x4 uv = *(const i32x4*)p;
  const float* lp = lab2 + tag*1600 + kc;
  f32x4 l0 = *(const f32x4*)lp;
  f32x4 l1 = *(const f32x4*)(lp+4);
  i32x4 q = (i32x4){ (int)pkbf16(hi16g(uv.x)*l0.y, lo16(uv.x)*l0.x),
                     (int)pkbf16(hi16g(uv.y)*l0.w, lo16(uv.y)*l0.z),
                     (int)pkbf16(hi16g(uv.z)*l1.y, lo16(uv.z)*l1.x),
                     (int)pkbf16(hi16g(uv.w)*l1.w, lo16(uv.w)*l1.z) };
  *(i32x4*)p = q;
}

// --------------------------------------------------------------- scorer ----
// scores = csum[r] - 2*sum_h r*V[h,r];  r = 1/(Eu*Ew+1) via bf16-domain magic.
// R20-exact: reads lab-fused uw2. 1024 blocks x 512 threads, LDS 25.7KB.
__device__ __forceinline__ unsigned rpair(int uvw, int wvw){
  f32x2 xu; xu.x = lo16(uvw); xu.y = hi16g(uvw);
  f32x2 xw; xw.x = lo16(wvw); xw.y = hi16g(wvw);
  f32x2 one2 = {1.0f, 1.0f};
  f32x2 p;
  asm("v_pk_fma_f32 %0, %1, %2, %3" : "=v"(p) : "v"(xu), "v"(xw), "v"(one2));
  unsigned pb = __builtin_amdgcn_perm(__float_as_uint(p.y), __float_as_uint(p.x), 0x07060302u);
  unsigned magic2 = 0x7EF37EF3u;
  unsigned y;
  asm("v_pk_sub_u16 %0, %1, %2" : "=v"(y) : "v"(magic2), "v"(pb));
  return y;
}

__global__ __launch_bounds__(512) void scorer_kernel(
    char* __restrict__ ws, const int* __restrict__ none_p,
    float* __restrict__ d_out)
{
  __shared__ ushort_t sw[16][804];
  const ushort_t* uw2 = (const ushort_t*)(ws + WS_UW2);
  const ushort_t* vf  = (const ushort_t*)(ws + WS_VFRAG);
  const float* csum   = (const float*)(ws + WS_CSUM);
  float* out_sc = d_out + 1024;
  int bx = blockIdx.x, tid = threadIdx.x;
  int b = bx >> 8, ti = (bx>>4)&15, tj = bx&15;
  int I0 = ti*16, J0 = tj*16, bS = b*256;

  for (int idx = tid; idx < 1600; idx += 512) {   // stage sw (already lab-fused)
    int row = idx / 100, c8 = idx - row*100, kc = c8*8;
    int grow = bS + J0 + row;
    *(i32x4*)&sw[row][kc] = *(const i32x4*)(uw2 + (size_t)grow*1600 + 800 + kc);
  }
  __syncthreads();

  int lane = tid & 63, w = tid >> 6;   // 8 waves
  int m16 = lane & 15, quad = lane >> 4;
  int none = *none_p;

  f32x4 acc[2];
  acc[0] = (f32x4){0.f,0.f,0.f,0.f};
  acc[1] = (f32x4){0.f,0.f,0.f,0.f};

  const ushort_t* su0 = uw2 + (size_t)(bS + I0 + w*2    )*1600 + quad*8;
  const ushort_t* su1 = uw2 + (size_t)(bS + I0 + w*2 + 1)*1600 + quad*8;
  const ushort_t* vlane = vf + lane*8;
  i32x4 bfc = *(const i32x4*)vlane;
  for (int c=0; c<25; c++) {
    i32x4 bfn;
    if (c < 24) bfn = *(const i32x4*)(vlane + (c+1)*512);
    int koff = c*32 + quad*8;
    i32x4 wv = *(const i32x4*)&sw[m16][koff];
    i32x4 uv0 = *(const i32x4*)(su0 + c*32);       // quad-broadcast, L1/L2
    i32x4 uv1 = *(const i32x4*)(su1 + c*32);
    bf16x8 bfrag = __builtin_bit_cast(bf16x8, bfc);
    {
      unsigned a0 = rpair(uv0.x, wv.x);
      unsigned a1 = rpair(uv0.y, wv.y);
      unsigned a2 = rpair(uv0.z, wv.z);
      unsigned a3 = rpair(uv0.w, wv.w);
      i32x4 avv = (i32x4){(int)a0,(int)a1,(int)a2,(int)a3};
      bf16x8 af = __builtin_bit_cast(bf16x8, avv);
      acc[0] = __builtin_amdgcn_mfma_f32_16x16x32_bf16(af, bfrag, acc[0], 0,0,0);
    }
    {
      unsigned a0 = rpair(uv1.x, wv.x);
      unsigned a1 = rpair(uv1.y, wv.y);
      unsigned a2 = rpair(uv1.z, wv.z);
      unsigned a3 = rpair(uv1.w, wv.w);
      i32x4 avv = (i32x4){(int)a0,(int)a1,(int)a2,(int)a3};
      bf16x8 af = __builtin_bit_cast(bf16x8, avv);
      acc[1] = __builtin_amdgcn_mfma_f32_16x16x32_bf16(af, bfrag, acc[1], 0,0,0);
    }
    bfc = bfn;
  }

  int r = m16;                         // D: col=lane&15 -> r, row=quad*4+reg -> j_local
  if (r < 12) {
    float cs = csum[r];
    #pragma unroll
    for (int it=0; it<2; it++) {
      int gi = I0 + w*2 + it;
      #pragma unroll
      for (int reg=0; reg<4; reg++) {
        int gj = J0 + quad*4 + reg;
        float v = __builtin_fmaf(-2.0f, acc[it][reg], cs);
        if (gi == gj && r == none) v = 100.0f;
        out_sc[(size_t)((bS + gi)*256 + gj)*12 + r] = v;
      }
    }
  }
}

extern "C" void kernel_launch(void* const* d_in, const int* in_sizes, int n_in,
                              void* d_out, int out_size, void* d_ws, size_t ws_size,
                              hipStream_t stream)
{
  const float* embed = (const float*)d_in[0];
  const float* lw    = (const float*)d_in[1];
  const float* lb    = (const float*)d_in[2];
  const float* st    = (const float*)d_in[3];
  const float* tr    = (const float*)d_in[4];
  const float* et    = (const float*)d_in[5];
  const float* lemb  = (const float*)d_in[6];
  const float* uw    = (const float*)d_in[7];
  const float* ub    = (const float*)d_in[8];
  const float* ww    = (const float*)d_in[9];
  const float* wb    = (const float*)d_in[10];
  const float* vw    = (const float*)d_in[11];
  const int* none_p  = (const int*)d_in[12];
  char* ws = (char*)d_ws;
  float* out = (float*)d_out;

  // zero the ner-done flag (graph-capturable async op)
  hipMemsetAsync(ws + WS_FLAG, 0, 64, stream);

  hipLaunchKernelGGL(main_kernel, dim3(765), dim3(256), 0, stream,
                     embed, lw, lb, lemb, uw, ub, ww, wb, vw,
                     st, tr, et, ws, out);
  hipLaunchKernelGGL(fuse_kernel, dim3(800), dim3(256), 0, stream, ws);
  hipLaunchKernelGGL(scorer_kernel, dim3(1024), dim3(512), 0, stream,
                     ws, none_p, out);
}

// Round 11
// 140.266 us; speedup vs baseline: 1.0939x; 1.0939x over previous
//
#include <hip/hip_runtime.h>

// BERT joint NER+relation head on MI355X (gfx950).
// Inputs: fp32. Output: fp32 flat [tags(1024) | scores(3145728)].
// R26: exact revert to R24 (best verified: 142.1us, absmax 0.2421875).
// Structure: K1 ner (256) / K2 main (509): GEMM || viterbi || lab2 ||
// vfrag || csum / K3 fuse (800, R15-exact) / K4 scorer (R20-exact).
// Viterbi: ds_bpermute 9-gather + fmax tree + setprio (latency floor
// ~155cyc/step, hidden under GEMM). Banned by evidence: cooperative
// launch (R17), grid barriers (R18/R19: LLC atomic serialization),
// scorer lab-fusion (R22/R23: unexplained identical fails), in-kernel
// ner->viterbi flag (R25: +26us unmodeled regression).

typedef unsigned short ushort_t;
typedef __attribute__((ext_vector_type(8))) short bf16x8;
typedef __attribute__((ext_vector_type(4))) float f32x4;
typedef __attribute__((ext_vector_type(2))) float f32x2;
typedef __attribute__((ext_vector_type(4))) int i32x4;
typedef unsigned long long u64;

#define C2F 2.8853900817779268f  // 2*log2(e)

// workspace offsets (bytes), all 16-aligned (ws_size = 256 MiB, plenty)
#define WS_UW2   0u         // ushort [1024][1600] : bf16(exp2(C2*(embed@[U|W]+bias))), lab-fused by K3
#define WS_NER   3276800u   // float  [1024][9]
#define WS_VFRAG 3313664u   // ushort [25][64][8]  : V as 16x16x32 B-fragments (bf16)
#define WS_LAB2  3339264u   // float  [9][1600]    : exp2(C2*(label_emb@[U|W][768:]))
#define WS_TAGS  3396864u   // int    [1024]
#define WS_CSUM  3400960u   // float  [12]         : colsum_r = sum_h V[h,r]

__device__ __forceinline__ unsigned f2b(float f){          // RNE, finite only
  unsigned u = __float_as_uint(f);
  return (u + 0x7FFFu + ((u>>16)&1u)) >> 16;
}
__device__ __forceinline__ unsigned pkbf16(float hi, float lo){
  return __builtin_amdgcn_perm(__float_as_uint(hi), __float_as_uint(lo), 0x07060302u);
}
__device__ __forceinline__ float lo16(int v){ return __uint_as_float(((unsigned)v)<<16); }
__device__ __forceinline__ float hi16g(int v){ return __uint_as_float((unsigned)v); }
// compose packed tag-functions (9 nibbles): R[t] = F[H[t]]
__device__ __forceinline__ u64 fcompose(u64 F, u64 H){
  u64 R = 0;
  #pragma unroll
  for (int t=0;t<9;t++){
    unsigned h = (unsigned)(H >> (4*t)) & 15u;
    unsigned v = (unsigned)(F >> (4*h)) & 15u;
    R |= (u64)v << (4*t);
  }
  return R;
}

// ------------------------------------------------ K1: ner (256 blocks) ----
__global__ __launch_bounds__(256) void ner_kernel(
    const float* __restrict__ embed, const float* __restrict__ lw,
    const float* __restrict__ lb,    char* __restrict__ ws)
{
  float* ner = (float*)(ws + WS_NER);
  int bx = blockIdx.x, tid = threadIdx.x;
  int w = tid >> 6, lane = tid & 63;
  int row = bx*4 + w;                  // < 1024
  float acc[9];
  #pragma unroll
  for (int i=0;i<9;i++) acc[i]=0.f;
  const float* erow = embed + row*768;
  for (int kk=0; kk<12; kk++) {
    int k = kk*64 + lane;
    float e = erow[k];
    #pragma unroll
    for (int i=0;i<9;i++) acc[i] = __builtin_fmaf(e, lw[k*9+i], acc[i]);
  }
  #pragma unroll
  for (int i=0;i<9;i++) {
    float v = acc[i];
    for (int off=32; off>0; off>>=1) v += __shfl_down(v, off);
    if (lane == 0) ner[row*9+i] = v + lb[i];
  }
}

// ------------------- K2: GEMM || viterbi || lab2 || vfrag || csum (509) ----
__global__ __launch_bounds__(256) void main_kernel(
    const float* __restrict__ embed, const float* __restrict__ lemb,
    const float* __restrict__ uw,    const float* __restrict__ ub,
    const float* __restrict__ ww,    const float* __restrict__ wb,
    const float* __restrict__ vw,
    const float* __restrict__ start_t, const float* __restrict__ trans,
    const float* __restrict__ end_t,
    char* __restrict__ ws, float* __restrict__ out_tags)
{
  __shared__ char smem[46848];     // union: GEMM As/Bs (10496) | viterbi (46848) | csum part
  int bx = blockIdx.x, tid = threadIdx.x;

  if (bx < 400) {                        // ---- GEMM, plain epilogue (R15-exact)
    ushort_t (*As)[40] = (ushort_t(*)[40])smem;            // [m][k] +8 pad
    ushort_t (*Bs)[42] = (ushort_t(*)[42])(smem + 5120);   // [n][k] +10 pad
    ushort_t* uw2 = (ushort_t*)(ws + WS_UW2);
    int bm = bx & 15, bn = bx >> 4;
    int M0 = bm*64, N0 = bn*64;
    int w = tid>>6, lane = tid&63;
    int wr = w>>1, wc = w&1;
    int m16 = lane&15, quad = lane>>4;
    int nl = tid>>2, k8 = (tid&3)<<3;
    int bnn = tid & 63, bw = tid >> 6;
    int gn = N0 + bnn;
    const float* bsrc = uw; int bcol = 0; bool bzero = true;
    if (gn < 798)                    { bsrc = uw; bcol = gn;     bzero = false; }
    else if (gn >= 800 && gn < 1598) { bsrc = ww; bcol = gn-800; bzero = false; }

    f32x4 acc[2][2];
    #pragma unroll
    for (int mi=0;mi<2;mi++)
      #pragma unroll
      for (int ni=0;ni<2;ni++) acc[mi][ni] = (f32x4){0.f,0.f,0.f,0.f};

    f32x4 a_lo, a_hi; float bvals[8];
    {
      const float* ap = &embed[(M0+nl)*768 + k8];
      a_lo = *(const f32x4*)ap; a_hi = *(const f32x4*)(ap+4);
      #pragma unroll
      for (int r=0;r<4;r++) {
        int kk = r*8 + bw*2;
        bvals[2*r]   = bzero ? 0.f : bsrc[(kk  )*798 + bcol];
        bvals[2*r+1] = bzero ? 0.f : bsrc[(kk+1)*798 + bcol];
      }
    }
    for (int k0=0; k0<768; k0+=32) {
      i32x4 av = (i32x4){ (int)pkbf16(a_lo.y,a_lo.x), (int)pkbf16(a_lo.w,a_lo.z),
                          (int)pkbf16(a_hi.y,a_hi.x), (int)pkbf16(a_hi.w,a_hi.z) };
      *(i32x4*)&As[nl][k8] = av;
      #pragma unroll
      for (int r=0;r<4;r++) {
        int kk = r*8 + bw*2;
        *(unsigned*)&Bs[bnn][kk] = pkbf16(bvals[2*r+1], bvals[2*r]);
      }
      __syncthreads();
      if (k0 + 32 < 768) {
        const float* ap = &embed[(M0+nl)*768 + k0 + 32 + k8];
        a_lo = *(const f32x4*)ap; a_hi = *(const f32x4*)(ap+4);
        #pragma unroll
        for (int r=0;r<4;r++) {
          int kk = r*8 + bw*2;
          bvals[2*r]   = bzero ? 0.f : bsrc[(k0+32+kk  )*798 + bcol];
          bvals[2*r+1] = bzero ? 0.f : bsrc[(k0+32+kk+1)*798 + bcol];
        }
      }
      bf16x8 a0 = *(const bf16x8*)&As[wr*32      + m16][quad*8];
      bf16x8 a1 = *(const bf16x8*)&As[wr*32 + 16 + m16][quad*8];
      bf16x8 b0 = *(const bf16x8*)&Bs[wc*32      + m16][quad*8];
      bf16x8 b1 = *(const bf16x8*)&Bs[wc*32 + 16 + m16][quad*8];
      acc[0][0] = __builtin_amdgcn_mfma_f32_16x16x32_bf16(a0,b0,acc[0][0],0,0,0);
      acc[0][1] = __builtin_amdgcn_mfma_f32_16x16x32_bf16(a0,b1,acc[0][1],0,0,0);
      acc[1][0] = __builtin_amdgcn_mfma_f32_16x16x32_bf16(a1,b0,acc[1][0],0,0,0);
      acc[1][1] = __builtin_amdgcn_mfma_f32_16x16x32_bf16(a1,b1,acc[1][1],0,0,0);
      __syncthreads();
    }
    #pragma unroll
    for (int mi=0;mi<2;mi++)
      #pragma unroll
      for (int ni=0;ni<2;ni++)
        #pragma unroll
        for (int reg=0;reg<4;reg++) {
          int gm = M0 + wr*32 + mi*16 + quad*4 + reg;
          int go = N0 + wc*32 + ni*16 + m16;
          float bias = 0.f;
          if (go < 798) bias = ub[go];
          else if (go >= 800 && go < 1598) bias = wb[go-800];
          float v = (acc[mi][ni][reg] + bias) * C2F;
          uw2[gm*1600 + go] = (ushort_t)f2b(__builtin_amdgcn_exp2f(v));
        }
  } else if (bx == 400) {                // ---- viterbi (hidden under GEMM)
    float* scores = (float*)smem;                    // [4][256][9] f32, 36864 B
    u64* pk = (u64*)(smem + 36864);                  // [4][256] packed funcs
    float* trl = (float*)(smem + 45056);             // [81]
    int* lastArr = (int*)(smem + 45384);             // [4]
    unsigned char* tagbuf = (unsigned char*)(smem + 45400);  // [4][256]
    const float* ner = (const float*)(ws + WS_NER);
    int* tags = (int*)(ws + WS_TAGS);
    int w = tid>>6, lane = tid&63;
    int b = w;
    int tt = lane < 9 ? lane : 8;
    if (tid < 81) trl[tid] = trans[tid];

    float tcol[9];
    #pragma unroll
    for (int p=0;p<9;p++) tcol[p] = trans[p*9+tt];
    const float* nb = ner + (b*256)*9 + tt;
    float score = start_t[tt] + nb[0];
    if (lane < 9) scores[(b*256 + 0)*9 + tt] = score;

    float cur[15], nxt[15];
    #pragma unroll
    for (int j=0;j<15;j++) cur[j] = nb[(1+j)*9];
    // gather lane p's score via explicit ds_bpermute (9 back-to-back issues,
    // one lgkm wait); bits identical to readlane/shfl path.
    #define GATHER(p) __uint_as_float(__builtin_amdgcn_ds_bpermute((p)<<2, __float_as_uint(score)))
    __builtin_amdgcn_s_setprio(1);
    for (int ch=0; ch<17; ch++) {
      int sb = 1 + ch*15;
      if (ch < 16) {
        #pragma unroll
        for (int j=0;j<15;j++) nxt[j] = nb[(sb+15+j)*9];
      }
      #pragma unroll
      for (int j=0;j<15;j++) {
        float g0=GATHER(0), g1=GATHER(1), g2=GATHER(2),
              g3=GATHER(3), g4=GATHER(4), g5=GATHER(5),
              g6=GATHER(6), g7=GATHER(7), g8=GATHER(8);
        float m0 = fmaxf(fmaxf(g0+tcol[0], g1+tcol[1]), g2+tcol[2]);
        float m1 = fmaxf(fmaxf(g3+tcol[3], g4+tcol[4]), g5+tcol[5]);
        float m2 = fmaxf(fmaxf(g6+tcol[6], g7+tcol[7]), g8+tcol[8]);
        score = fmaxf(fmaxf(m0,m1),m2) + cur[j];
        if (lane < 9) scores[(b*256 + sb + j)*9 + tt] = score;
      }
      #pragma unroll
      for (int j=0;j<15;j++) cur[j] = nxt[j];
    }
    __builtin_amdgcn_s_setprio(0);
    #undef GATHER
    {
      float fin = score + end_t[tt];
      #define RLF(p) __uint_as_float(__builtin_amdgcn_readlane(__float_as_uint(fin), p))
      float bv = RLF(0); int ba = 0;
      #pragma unroll
      for (int p=1;p<9;p++) { float v = RLF(p); if (v > bv) { bv = v; ba = p; } }
      if (lane == 0) lastArr[b] = ba;
      #undef RLF
    }
    __syncthreads();

    for (int idx = tid; idx < 1024; idx += 256) {
      int bb = idx >> 8, s = idx & 255;
      u64 f;
      if (s == 255) f = 0x876543210ULL;              // identity
      else {
        const float* srow = &scores[(bb*256 + s)*9];
        float sp[9];
        #pragma unroll
        for (int p=0;p<9;p++) sp[p] = srow[p];
        f = 0;
        #pragma unroll
        for (int t=0;t<9;t++) {
          float best = sp[0] + trl[t]; int arg = 0;
          #pragma unroll
          for (int p=1;p<9;p++) {
            float v = sp[p] + trl[p*9 + t];
            if (v > best) { best = v; arg = p; }
          }
          f |= (u64)arg << (4*t);
        }
      }
      pk[bb*256 + s] = f;
    }
    __syncthreads();

    if (tid < 64) {
      int cb = tid >> 4, c = tid & 15;
      u64 fs[16];
      #pragma unroll
      for (int j=0;j<16;j++) fs[j] = pk[cb*256 + c*16 + j];
      u64 G = fs[15];
      #pragma unroll
      for (int j=14;j>=0;j--) G = fcompose(fs[j], G);
      u64 F = G;
      #pragma unroll
      for (int d=1; d<16; d<<=1) {
        u64 H = __shfl(F, tid + d);
        if (c + d < 16) F = fcompose(F, H);
      }
      int last = lastArr[cb];
      u64 Hn = __shfl(F, (c==15) ? tid : tid+1);
      unsigned t_cur = (c==15) ? (unsigned)last
                               : (unsigned)((Hn >> (4*last)) & 15u);
      #pragma unroll
      for (int j=15;j>=0;j--) {
        t_cur = (unsigned)((fs[j] >> (4*t_cur)) & 15u);
        tagbuf[cb*256 + c*16 + j] = (unsigned char)t_cur;
      }
    }
    __syncthreads();

    for (int idx = tid; idx < 1024; idx += 256) {
      int tg = (int)tagbuf[idx];
      tags[idx] = tg;
      out_tags[idx] = (float)tg;
    }
  } else if (bx < 458) {                 // ---- lab2[g][n] = exp2(C2*lemb[g]@[U|W][768:,n])
    float* lab2 = (float*)(ws + WS_LAB2);
    int idx = (bx-401)*256 + tid;
    if (idx < 14400) {
      int g = idx / 1600, n = idx - g*1600;
      const float* X = (n < 800) ? uw : ww;
      int nn = (n < 800) ? n : (n - 800);
      float v = 1.0f;                    // pad columns: multiplicative identity
      if (nn < 798) {
        float s = 0.f;
        #pragma unroll                   // pipeline the 30 strided loads
        for (int l=0;l<30;l++)
          s = __builtin_fmaf(lemb[g*30+l], X[(768+l)*798 + nn], s);
        v = __builtin_amdgcn_exp2f(s * C2F);
      }
      lab2[idx] = v;
    }
  } else if (bx < 508) {                 // ---- V B-fragments
    ushort_t* vf = (ushort_t*)(ws + WS_VFRAG);
    int idx = (bx-458)*256 + tid;        // < 12800
    if (idx < 12800) {
      int jj = idx & 7, lane = (idx>>3) & 63, c = idx >> 9;
      int h = c*32 + ((lane>>4)<<3) + jj;
      int n = lane & 15;
      vf[idx] = (h < 798 && n < 12) ? (ushort_t)f2b(vw[h*12 + n]) : (ushort_t)0;
    }
  } else {                               // ---- csum[r] = sum_h V[h,r], 256-thread + LDS reduce
    float* part = (float*)smem;          // [16][12]
    float* csum = (float*)(ws + WS_CSUM);
    int r = tid & 15, sub = tid >> 4;    // 16 subs x 16 slots (r<12 active)
    if (r < 12 && sub < 16) {
      float s = 0.f;
      for (int h = sub; h < 798; h += 16) s += vw[h*12 + r];
      part[sub*12 + r] = s;
    }
    __syncthreads();
    if (tid < 12) {
      float t = 0.f;
      #pragma unroll
      for (int k = 0; k < 16; k++) t += part[k*12 + tid];
      csum[tid] = t;
    }
  }
}

// ---------------------------------- K3: fuse Elab[tag] into uw2 (in place)
__global__ __launch_bounds__(256) void fuse_kernel(char* __restrict__ ws)
{
  ushort_t* uw2      = (ushort_t*)(ws + WS_UW2);
  const float* lab2  = (const float*)(ws + WS_LAB2);
  const int* tags    = (const int*)(ws + WS_TAGS);
  int idx = blockIdx.x*256 + threadIdx.x;          // < 204800 vec8 chunks
  int row = idx / 200, c8 = idx - row*200, kc = c8*8;
  int tag = tags[row];
  ushort_t* p = uw2 + (size_t)row*1600 + kc;
  i32x4 uv = *(const i32x4*)p;
  const float* lp = lab2 + tag*1600 + kc;
  f32x4 l0 = *(const f32x4*)lp;
  f32x4 l1 = *(const f32x4*)(lp+4);
  i32x4 q = (i32x4){ (int)pkbf16(hi16g(uv.x)*l0.y, lo16(uv.x)*l0.x),
                     (int)pkbf16(hi16g(uv.y)*l0.w, lo16(uv.y)*l0.z),
                     (int)pkbf16(hi16g(uv.z)*l1.y, lo16(uv.z)*l1.x),
                     (int)pkbf16(hi16g(uv.w)*l1.w, lo16(uv.w)*l1.z) };
  *(i32x4*)p = q;
}

// --------------------------------------------------------------- scorer ----
// scores = csum[r] - 2*sum_h r*V[h,r];  r = 1/(Eu*Ew+1) via bf16-domain magic.
// R20-exact: reads lab-fused uw2. 1024 blocks x 512 threads, LDS 25.7KB.
__device__ __forceinline__ unsigned rpair(int uvw, int wvw){
  f32x2 xu; xu.x = lo16(uvw); xu.y = hi16g(uvw);
  f32x2 xw; xw.x = lo16(wvw); xw.y = hi16g(wvw);
  f32x2 one2 = {1.0f, 1.0f};
  f32x2 p;
  asm("v_pk_fma_f32 %0, %1, %2, %3" : "=v"(p) : "v"(xu), "v"(xw), "v"(one2));
  unsigned pb = __builtin_amdgcn_perm(__float_as_uint(p.y), __float_as_uint(p.x), 0x07060302u);
  unsigned magic2 = 0x7EF37EF3u;
  unsigned y;
  asm("v_pk_sub_u16 %0, %1, %2" : "=v"(y) : "v"(magic2), "v"(pb));
  return y;
}

__global__ __launch_bounds__(512) void scorer_kernel(
    char* __restrict__ ws, const int* __restrict__ none_p,
    float* __restrict__ d_out)
{
  __shared__ ushort_t sw[16][804];
  const ushort_t* uw2 = (const ushort_t*)(ws + WS_UW2);
  const ushort_t* vf  = (const ushort_t*)(ws + WS_VFRAG);
  const float* csum   = (const float*)(ws + WS_CSUM);
  float* out_sc = d_out + 1024;
  int bx = blockIdx.x, tid = threadIdx.x;
  int b = bx >> 8, ti = (bx>>4)&15, tj = bx&15;
  int I0 = ti*16, J0 = tj*16, bS = b*256;

  for (int idx = tid; idx < 1600; idx += 512) {   // stage sw (already lab-fused)
    int row = idx / 100, c8 = idx - row*100, kc = c8*8;
    int grow = bS + J0 + row;
    *(i32x4*)&sw[row][kc] = *(const i32x4*)(uw2 + (size_t)grow*1600 + 800 + kc);
  }
  __syncthreads();

  int lane = tid & 63, w = tid >> 6;   // 8 waves
  int m16 = lane & 15, quad = lane >> 4;
  int none = *none_p;

  f32x4 acc[2];
  acc[0] = (f32x4){0.f,0.f,0.f,0.f};
  acc[1] = (f32x4){0.f,0.f,0.f,0.f};

  const ushort_t* su0 = uw2 + (size_t)(bS + I0 + w*2    )*1600 + quad*8;
  const ushort_t* su1 = uw2 + (size_t)(bS + I0 + w*2 + 1)*1600 + quad*8;
  const ushort_t* vlane = vf + lane*8;
  i32x4 bfc = *(const i32x4*)vlane;
  for (int c=0; c<25; c++) {
    i32x4 bfn;
    if (c < 24) bfn = *(const i32x4*)(vlane + (c+1)*512);
    int koff = c*32 + quad*8;
    i32x4 wv = *(const i32x4*)&sw[m16][koff];
    i32x4 uv0 = *(const i32x4*)(su0 + c*32);       // quad-broadcast, L1/L2
    i32x4 uv1 = *(const i32x4*)(su1 + c*32);
    bf16x8 bfrag = __builtin_bit_cast(bf16x8, bfc);
    {
      unsigned a0 = rpair(uv0.x, wv.x);
      unsigned a1 = rpair(uv0.y, wv.y);
      unsigned a2 = rpair(uv0.z, wv.z);
      unsigned a3 = rpair(uv0.w, wv.w);
      i32x4 avv = (i32x4){(int)a0,(int)a1,(int)a2,(int)a3};
      bf16x8 af = __builtin_bit_cast(bf16x8, avv);
      acc[0] = __builtin_amdgcn_mfma_f32_16x16x32_bf16(af, bfrag, acc[0], 0,0,0);
    }
    {
      unsigned a0 = rpair(uv1.x, wv.x);
      unsigned a1 = rpair(uv1.y, wv.y);
      unsigned a2 = rpair(uv1.z, wv.z);
      unsigned a3 = rpair(uv1.w, wv.w);
      i32x4 avv = (i32x4){(int)a0,(int)a1,(int)a2,(int)a3};
      bf16x8 af = __builtin_bit_cast(bf16x8, avv);
      acc[1] = __builtin_amdgcn_mfma_f32_16x16x32_bf16(af, bfrag, acc[1], 0,0,0);
    }
    bfc = bfn;
  }

  int r = m16;                         // D: col=lane&15 -> r, row=quad*4+reg -> j_local
  if (r < 12) {
    float cs = csum[r];
    #pragma unroll
    for (int it=0; it<2; it++) {
      int gi = I0 + w*2 + it;
      #pragma unroll
      for (int reg=0; reg<4; reg++) {
        int gj = J0 + quad*4 + reg;
        float v = __builtin_fmaf(-2.0f, acc[it][reg], cs);
        if (gi == gj && r == none) v = 100.0f;
        out_sc[(size_t)((bS + gi)*256 + gj)*12 + r] = v;
      }
    }
  }
}

extern "C" void kernel_launch(void* const* d_in, const int* in_sizes, int n_in,
                              void* d_out, int out_size, void* d_ws, size_t ws_size,
                              hipStream_t stream)
{
  const float* embed = (const float*)d_in[0];
  const float* lw    = (const float*)d_in[1];
  const float* lb    = (const float*)d_in[2];
  const float* st    = (const float*)d_in[3];
  const float* tr    = (const float*)d_in[4];
  const float* et    = (const float*)d_in[5];
  const float* lemb  = (const float*)d_in[6];
  const float* uw    = (const float*)d_in[7];
  const float* ub    = (const float*)d_in[8];
  const float* ww    = (const float*)d_in[9];
  const float* wb    = (const float*)d_in[10];
  const float* vw    = (const float*)d_in[11];
  const int* none_p  = (const int*)d_in[12];
  char* ws = (char*)d_ws;
  float* out = (float*)d_out;

  hipLaunchKernelGGL(ner_kernel, dim3(256), dim3(256), 0, stream,
                     embed, lw, lb, ws);
  hipLaunchKernelGGL(main_kernel, dim3(509), dim3(256), 0, stream,
                     embed, lemb, uw, ub, ww, wb, vw, st, tr, et, ws, out);
  hipLaunchKernelGGL(fuse_kernel, dim3(800), dim3(256), 0, stream, ws);
  hipLaunchKernelGGL(scorer_kernel, dim3(1024), dim3(512), 0, stream,
                     ws, none_p, out);
}